// Round 8
// baseline (350.942 us; speedup 1.0000x reference)
//
#include <hip/hip_runtime.h>
#include <math.h>

#define BATCH 8
#define NTOK  4096
#define DIM   64
#define BM    128
#define NT    (NTOK / BM)            // 32 tiles per dim
#define TPB   (NT * (NT + 1) / 2)    // 528 upper-tri tile pairs per batch
#define TOTAL (BATCH * TPB)          // 4224 tile-pair blocks
#define REP   16                     // AMPLIFICATION PROBE — see header comment
#define KAPPA 0.5f
#define LOG2E 1.4426950408889634f
#define LN2   0.6931471805599453f
#define M2FIX 48.0f                  // fixed log2-domain shift (R4-R7 verified)

typedef _Float16 f16x8 __attribute__((ext_vector_type(8)));
typedef float    f32x16 __attribute__((ext_vector_type(16)));

__device__ __forceinline__ float EXP2(float x) {
#if __has_builtin(__builtin_amdgcn_exp2f)
    return __builtin_amdgcn_exp2f(x);
#else
    return __expf(x * LN2);
#endif
}

// ---- kernel 0: one-time f32 -> f16 image (RTE casts). ----
__global__ __launch_bounds__(256)
void conv_f16(const float* __restrict__ emb, f16x8* __restrict__ o16) {
    const size_t i = (size_t)blockIdx.x * 256 + threadIdx.x;  // 262144 units
    const float4 v0 = *(const float4*)(emb + i * 8);
    const float4 v1 = *(const float4*)(emb + i * 8 + 4);
    f16x8 p;
    p[0] = (_Float16)v0.x; p[1] = (_Float16)v0.y;
    p[2] = (_Float16)v0.z; p[3] = (_Float16)v0.w;
    p[4] = (_Float16)v1.x; p[5] = (_Float16)v1.y;
    p[6] = (_Float16)v1.z; p[7] = (_Float16)v1.w;
    o16[i] = p;
}

// ---- kernel 1: MEASUREMENT ROUND (R8). This is R6's kernel (best recent:
// 81.1 us total) with the whole body repeated REP=16 times. Rationale:
// R1 calibration bounds gram at ~30 us vs a ~5 us pipe floor, but gram has
// been invisible in top-5 rocprof output since R1 (41-us workspace fills
// flood it), and 7 structural variants were all neutral. The repeat makes
// gram the top dispatch (its OWN VALUBusy/MfmaUtil/FETCH become readable)
// and the marginal per-pass cost = (dur_us - 82)/15 distinguishes
// "real per-pass stall" (total ~500) from "per-dispatch overhead" (~150).
// Stores are idempotent across reps -> output bit-identical to R6.
__global__ __launch_bounds__(256, 4)
void gram_lse_partial(const f16x8* __restrict__ w16, float* __restrict__ ws) {
    __shared__ f16x8 S[2048];      // 32 KB: As = S[0..1023], Bs = S[1024..2047]

    const int tid  = threadIdx.x;
    const int lane = tid & 63;
    const int w    = tid >> 6;
    const int p    = blockIdx.x;
    const int bb   = (p & 7) * TPB + (p >> 3);   // XCD-chunked swizzle (T1)
    const int b    = bb / TPB;                   // == p & 7
    int t = bb - b * TPB;
    int ti = 0;
    while (t >= NT - ti) { t -= NT - ti; ++ti; }
    const int tj = ti + t;

    const char* pA16 = (const char*)(w16 + ((size_t)b * NTOK + (size_t)ti * BM) * 8);
    const char* pB16 = (const char*)(w16 + ((size_t)b * NTOK + (size_t)tj * BM) * 8);

    const int half = lane >> 5;    // k-half within fragment
    const int ln31 = lane & 31;
    const int waveR = (w & 1) * 64;
    const int waveC = (w >> 1) * 64;
    const float c2 = KAPPA * LOG2E;

#pragma unroll 1
    for (int rep = 0; rep < REP; ++rep) {
        // ---- staging: 8 global_load_lds_dwordx4 per thread ----
        {
            const char* pbase  = (w < 2) ? pA16 : pB16;     // wave-uniform
            const int   upBase = (w & 1) * 512 + lane;
#pragma unroll
            for (int q = 0; q < 8; ++q) {
                const int up  = upBase + q * 64;
                const int g   = up >> 7;
                const int rp  = up & 127;
                const int off = (((rp ^ g) << 7) | (g << 4));
                __builtin_amdgcn_global_load_lds(
                    (const __attribute__((address_space(1))) void*)(pbase + off),
                    (__attribute__((address_space(3))) void*)&S[(size_t)w * 512 + q * 64],
                    16, 0, 0);
            }
        }
        __syncthreads();

        // ---- MFMA: wave computes a 64x64 subtile (2x2 of 32x32, K=64) ----
        f32x16 acc00 = {}, acc01 = {}, acc10 = {}, acc11 = {};
#pragma unroll
        for (int s = 0; s < 4; ++s) {
            const int g = 2 * s + half;
            const f16x8 a0 = S[g * BM + ((waveR + ln31) ^ g)];
            const f16x8 a1 = S[g * BM + ((waveR + 32 + ln31) ^ g)];
            const f16x8 b0 = S[1024 + g * BM + ((waveC + ln31) ^ g)];
            const f16x8 b1 = S[1024 + g * BM + ((waveC + 32 + ln31) ^ g)];
            acc00 = __builtin_amdgcn_mfma_f32_32x32x16_f16(a0, b0, acc00, 0, 0, 0);
            acc01 = __builtin_amdgcn_mfma_f32_32x32x16_f16(a0, b1, acc01, 0, 0, 0);
            acc10 = __builtin_amdgcn_mfma_f32_32x32x16_f16(a1, b0, acc10, 0, 0, 0);
            acc11 = __builtin_amdgcn_mfma_f32_32x32x16_f16(a1, b1, acc11, 0, 0, 0);
        }
        __syncthreads();           // LDS reusable next rep

        // ---- epilogue: fixed-shift sum-exp2, no max pass ----
        float s0 = 0.f, s1 = 0.f, s2 = 0.f, s3 = 0.f;
#pragma unroll
        for (int e = 0; e < 16; ++e) {
            s0 += EXP2(fmaf(c2, acc00[e], -M2FIX));
            s1 += EXP2(fmaf(c2, acc01[e], -M2FIX));
            s2 += EXP2(fmaf(c2, acc10[e], -M2FIX));
            s3 += EXP2(fmaf(c2, acc11[e], -M2FIX));
        }
        float lsum = (s0 + s1) + (s2 + s3);
#pragma unroll
        for (int off = 32; off > 0; off >>= 1)
            lsum += __shfl_xor(lsum, off);

        if (lane == 0) {
            const float wgt = (ti == tj) ? 1.f : 2.f;
            ws[4 * (size_t)bb + w] = wgt * lsum;   // idempotent across reps
        }
    }
}

// ---- kernel 2: 1 block, 8 waves; wave w sums batch w's TPB*4 = 2112 wave
// partials (weights already applied) and converts back to natural log.
__global__ __launch_bounds__(512)
void reduce_lse(const float* __restrict__ ws, float* __restrict__ out) {
    const int tid  = threadIdx.x;
    const int w    = tid >> 6;
    const int lane = tid & 63;
    __shared__ float lse8[BATCH];

    const float* p = ws + (size_t)w * TPB * 4;   // batch w: 2112 floats
    float s = 0.f;
#pragma unroll
    for (int c = 0; c < 33; ++c) s += p[lane + 64 * c];
#pragma unroll
    for (int off = 32; off > 0; off >>= 1) s += __shfl_xor(s, off);

    if (lane == 0) lse8[w] = LN2 * (M2FIX + log2f(s));   // natural-log LSE
    __syncthreads();
    if (tid == 0) {
        float a = 0.f;
        for (int i = 0; i < BATCH; ++i) a += lse8[i];
        out[0] = a * (1.f / BATCH);
    }
}

extern "C" void kernel_launch(void* const* d_in, const int* in_sizes, int n_in,
                              void* d_out, int out_size, void* d_ws, size_t ws_size,
                              hipStream_t stream) {
    const float* emb = (const float*)d_in[0];
    float* out = (float*)d_out;
    f16x8* w16 = (f16x8*)d_ws;                            // 4 MB f16 image
    float* prt = (float*)((char*)d_ws + (4u << 20));      // 67,584 B partials

    conv_f16<<<NTOK * BATCH * DIM / 8 / 256, 256, 0, stream>>>(emb, w16);
    gram_lse_partial<<<TOTAL, 256, 0, stream>>>(w16, prt);
    reduce_lse<<<1, 512, 0, stream>>>(prt, out);
}

// Round 9
// 79.827 us; speedup vs baseline: 4.3963x; 4.3963x over previous
//
#include <hip/hip_runtime.h>
#include <math.h>

#define BATCH 8
#define NTOK  4096
#define DIM   64
#define BM    128
#define NT    (NTOK / BM)            // 32 tiles per dim
#define TPB   (NT * (NT + 1) / 2)    // 528 upper-tri tile pairs per batch
#define TOTAL (BATCH * TPB)          // 4224 tile-pair blocks
#define KAPPA 0.5f
#define LOG2E 1.4426950408889634f
#define LN2   0.6931471805599453f
#define M2FIX 48.0f                  // fixed log2-domain shift (R4-R8 verified)

typedef _Float16 f16x8 __attribute__((ext_vector_type(8)));
typedef float    f32x16 __attribute__((ext_vector_type(16)));

__device__ __forceinline__ float EXP2(float x) {
#if __has_builtin(__builtin_amdgcn_exp2f)
    return __builtin_amdgcn_exp2f(x);
#else
    return __expf(x * LN2);
#endif
}

// ---- kernel 0: one-time f32 -> f16 image (RTE casts). ----
__global__ __launch_bounds__(256)
void conv_f16(const float* __restrict__ emb, f16x8* __restrict__ o16) {
    const size_t i = (size_t)blockIdx.x * 256 + threadIdx.x;  // 262144 units
    const float4 v0 = *(const float4*)(emb + i * 8);
    const float4 v1 = *(const float4*)(emb + i * 8 + 4);
    f16x8 p;
    p[0] = (_Float16)v0.x; p[1] = (_Float16)v0.y;
    p[2] = (_Float16)v0.z; p[3] = (_Float16)v0.w;
    p[4] = (_Float16)v1.x; p[5] = (_Float16)v1.y;
    p[6] = (_Float16)v1.z; p[7] = (_Float16)v1.w;
    o16[i] = p;
}

// ---- kernel 1: gram, occupancy round (R9).
// R8 probe: gram body is ~18-24 us REAL time even fully L2-warm (FETCH 2.8MB,
// HBM 0.2%) with VALUBusy 44% / MfmaUtil 19% / Occupancy 41% -> execution-
// bound, trans+VALU pipe underfed. Limiter was registers: 4 live f32x16
// accumulators (64 AGPR) + 64 VGPR = 128 regs -> 4 waves/SIMD.
// Fix: quadrant-at-a-time MFMA (one acc live, epilogue folded in per
// quadrant, regs reused; '#pragma unroll 1' pins the shape) -> ~50 regs ->
// __launch_bounds__(256,5): 5 blocks/CU, LDS 5x32KB = 160KB exact,
// 20 waves/CU. LDS reads double (32/wave) but port has 3x headroom, 0 conflicts.
__global__ __launch_bounds__(256, 5)
void gram_lse_partial(const f16x8* __restrict__ w16, float* __restrict__ ws) {
    __shared__ f16x8 S[2048];      // 32 KB: As = S[0..1023], Bs = S[1024..2047]

    const int tid  = threadIdx.x;
    const int lane = tid & 63;
    const int w    = tid >> 6;
    const int p    = blockIdx.x;
    const int bb   = (p & 7) * TPB + (p >> 3);   // XCD-chunked swizzle (T1)
    const int b    = bb / TPB;                   // == p & 7
    int t = bb - b * TPB;
    int ti = 0;
    while (t >= NT - ti) { t -= NT - ti; ++ti; }
    const int tj = ti + t;

    const char* pA16 = (const char*)(w16 + ((size_t)b * NTOK + (size_t)ti * BM) * 8);
    const char* pB16 = (const char*)(w16 + ((size_t)b * NTOK + (size_t)tj * BM) * 8);

    // ---- staging: 8 global_load_lds_dwordx4 per thread (verified R3-R8) ----
    // LDS dest linear (wave-uniform base + lane*16); XOR swizzle realized on
    // the per-lane GLOBAL source address (rule 21).
    {
        const char* pbase  = (w < 2) ? pA16 : pB16;     // wave-uniform
        const int   upBase = (w & 1) * 512 + lane;
#pragma unroll
        for (int q = 0; q < 8; ++q) {
            const int up  = upBase + q * 64;
            const int g   = up >> 7;
            const int rp  = up & 127;
            const int off = (((rp ^ g) << 7) | (g << 4));
            __builtin_amdgcn_global_load_lds(
                (const __attribute__((address_space(1))) void*)(pbase + off),
                (__attribute__((address_space(3))) void*)&S[(size_t)w * 512 + q * 64],
                16, 0, 0);
        }
    }
    __syncthreads();   // compiler emits vmcnt(0) drain before s_barrier

    // ---- quadrant loop: one 32x32 acc live at a time; epilogue folded in ----
    const int half = lane >> 5;    // k-half within fragment
    const int ln31 = lane & 31;
    const int waveR = (w & 1) * 64;
    const int waveC = (w >> 1) * 64;
    const float c2 = KAPPA * LOG2E;

    float s0 = 0.f, s1 = 0.f, s2 = 0.f, s3 = 0.f;
#pragma unroll 1
    for (int q = 0; q < 4; ++q) {
        const int ra = waveR + (q >> 1) * 32 + ln31;   // A-fragment row
        const int rb = waveC + (q & 1) * 32 + ln31;    // B-fragment row
        f32x16 acc = {};
#pragma unroll
        for (int s = 0; s < 4; ++s) {
            const int g = 2 * s + half;
            acc = __builtin_amdgcn_mfma_f32_32x32x16_f16(
                S[g * BM + (ra ^ g)], S[1024 + g * BM + (rb ^ g)], acc, 0, 0, 0);
        }
        // fixed-shift sum-exp2 (R4-R8 verified numerics), 4 chains for ILP
#pragma unroll
        for (int e = 0; e < 16; e += 4) {
            s0 += EXP2(fmaf(c2, acc[e],     -M2FIX));
            s1 += EXP2(fmaf(c2, acc[e + 1], -M2FIX));
            s2 += EXP2(fmaf(c2, acc[e + 2], -M2FIX));
            s3 += EXP2(fmaf(c2, acc[e + 3], -M2FIX));
        }
    }
    float lsum = (s0 + s1) + (s2 + s3);
#pragma unroll
    for (int off = 32; off > 0; off >>= 1)
        lsum += __shfl_xor(lsum, off);

    if (lane == 0) {
        const float wgt = (ti == tj) ? 1.f : 2.f;
        ws[4 * (size_t)bb + w] = wgt * lsum;   // logical-bb layout for reduce
    }
}

// ---- kernel 2: 1 block, 8 waves; wave w sums batch w's TPB*4 = 2112 wave
// partials (weights already applied) and converts back to natural log.
__global__ __launch_bounds__(512)
void reduce_lse(const float* __restrict__ ws, float* __restrict__ out) {
    const int tid  = threadIdx.x;
    const int w    = tid >> 6;
    const int lane = tid & 63;
    __shared__ float lse8[BATCH];

    const float* p = ws + (size_t)w * TPB * 4;   // batch w: 2112 floats
    float s = 0.f;
#pragma unroll
    for (int c = 0; c < 33; ++c) s += p[lane + 64 * c];
#pragma unroll
    for (int off = 32; off > 0; off >>= 1) s += __shfl_xor(s, off);

    if (lane == 0) lse8[w] = LN2 * (M2FIX + log2f(s));   // natural-log LSE
    __syncthreads();
    if (tid == 0) {
        float a = 0.f;
        for (int i = 0; i < BATCH; ++i) a += lse8[i];
        out[0] = a * (1.f / BATCH);
    }
}

extern "C" void kernel_launch(void* const* d_in, const int* in_sizes, int n_in,
                              void* d_out, int out_size, void* d_ws, size_t ws_size,
                              hipStream_t stream) {
    const float* emb = (const float*)d_in[0];
    float* out = (float*)d_out;
    f16x8* w16 = (f16x8*)d_ws;                            // 4 MB f16 image
    float* prt = (float*)((char*)d_ws + (4u << 20));      // 67,584 B partials

    conv_f16<<<NTOK * BATCH * DIM / 8 / 256, 256, 0, stream>>>(emb, w16);
    gram_lse_partial<<<TOTAL, 256, 0, stream>>>(w16, prt);
    reduce_lse<<<1, 512, 0, stream>>>(prt, out);
}